// Round 1
// 3917.057 us; speedup vs baseline: 1.0212x; 1.0212x over previous
//
#include <hip/hip_runtime.h>
#include <hip/hip_bf16.h>
#include <stdint.h>

typedef __attribute__((ext_vector_type(8))) short bf16x8;
typedef __attribute__((ext_vector_type(4))) float floatx4;

#define DEV __device__ __forceinline__

DEV void gl_lds16(const void* g, void* lds) {
    __builtin_amdgcn_global_load_lds(
        (const __attribute__((address_space(1))) unsigned int*)g,
        (__attribute__((address_space(3))) unsigned int*)lds, 16, 0, 0);
}

// counted waits + raw barrier (compiler memory fences around, rule #18)
#define WAIT_VM4() asm volatile("s_waitcnt vmcnt(4)" ::: "memory")
#define WAIT_VM0() asm volatile("s_waitcnt vmcnt(0)" ::: "memory")
#define BAR()                              \
    do {                                   \
        __builtin_amdgcn_s_barrier();      \
        asm volatile("" ::: "memory");     \
    } while (0)

// ---------------------------------------------------------------------------
// Gather-GEMM-scatter sparse conv:  Out[om[p]] += A[im[p]] @ W[koff]
// A: [Nin][K] bf16 (row stride == K == Cin)
// BT: [Koff][256][K] bf16 (W transposed: BT[k][n][kk] = W[k][kk][n])
// Tile: BM=128 pairs x BN=128 ch x BK=32, 4 waves (2x2), 64x64 per wave.
// LDS layout quad-major: element block (row r, quad q) at byte q*2048 + r*16.
//
// Software pipeline (T3/T4 minimum): 3 LDS buffers, depth-2 prefetch.
// Per K-step: s_waitcnt vmcnt(4) (leave next tile's 4 loads in flight)
// -> s_barrier -> stage step+2 -> ds_read/MFMA step.  Never vmcnt(0) in the
// main loop; 8 gather loads stay in flight across every barrier.
// Overwrite safety: stage(k+2) targets buffer (k-1)%3 whose reads finished
// before this step's barrier (lgkmcnt waited before the MFMAs).
// ---------------------------------------------------------------------------
template <int KSTEPS>
__global__ __launch_bounds__(256) void spconv_kernel(
    const __hip_bfloat16* __restrict__ A, const __hip_bfloat16* __restrict__ BT,
    const int* __restrict__ in_map, const int* __restrict__ out_map,
    float* __restrict__ Out, int M) {
    constexpr int K = KSTEPS * 32;
    __shared__ __align__(16) char Abuf[3][8192];
    __shared__ __align__(16) char Bbuf[3][8192];
    __shared__ int om_s[128];

    const int tid = threadIdx.x;
    const int w = tid >> 6;
    const int l = tid & 63;
    const int koff = blockIdx.z;
    const int m0 = blockIdx.x * 128;
    const int n0 = blockIdx.y * 128;

    const int* im = in_map + (size_t)koff * M;
    const int* om = out_map + (size_t)koff * M;

    if (tid < 128) {
        int p = m0 + tid;
        om_s[tid] = (p < M) ? om[p] : -1;
    }

    // staging: each lane owns one tile row (rS), two 16B quads (q0, q0+2)
    const int rS = (w & 1) * 64 + l;
    int prow = m0 + rS;
    if (prow > M - 1) prow = M - 1;
    const char* a_src = (const char*)(A + (size_t)im[prow] * K);
    const char* b_src =
        (const char*)(BT + ((size_t)koff * 256 + n0 + rS) * (size_t)K);
    const int so0 = (w >> 1) * 16;  // byte offset of quad q0 within 64B k-chunk
    const int so1 = so0 + 32;       // quad q0+2
    const int dA = w * 1024 + l * 16;

    floatx4 acc[4][4];
#pragma unroll
    for (int i = 0; i < 4; i++)
#pragma unroll
        for (int j = 0; j < 4; j++) acc[i][j] = (floatx4)0.0f;

    const int wm = w & 1, wn = w >> 1;
    const int lm = l & 15, lq = l >> 4;

    auto stage = [&](int buf, int ks) {
        const int kb = ks * 64;  // 32 bf16 elements = 64 bytes
        gl_lds16(a_src + kb + so0, &Abuf[buf][dA]);
        gl_lds16(a_src + kb + so1, &Abuf[buf][dA + 4096]);
        gl_lds16(b_src + kb + so0, &Bbuf[buf][dA]);
        gl_lds16(b_src + kb + so1, &Bbuf[buf][dA + 4096]);
    };

    auto compute = [&](int buf) {
        bf16x8 af[4], bf[4];
#pragma unroll
        for (int mt = 0; mt < 4; mt++)
            af[mt] = *(const bf16x8*)(&Abuf[buf][lq * 2048 +
                                                 (wm * 64 + mt * 16 + lm) * 16]);
#pragma unroll
        for (int nt = 0; nt < 4; nt++)
            bf[nt] = *(const bf16x8*)(&Bbuf[buf][lq * 2048 +
                                                 (wn * 64 + nt * 16 + lm) * 16]);
#pragma unroll
        for (int mt = 0; mt < 4; mt++)
#pragma unroll
            for (int nt = 0; nt < 4; nt++)
                acc[mt][nt] = __builtin_amdgcn_mfma_f32_16x16x32_bf16(
                    af[mt], bf[nt], acc[mt][nt], 0, 0, 0);
    };

    static_assert(KSTEPS >= 3, "pipeline needs >=3 K-steps");
    stage(0, 0);
    stage(1, 1);

    for (int ks = 0; ks < KSTEPS - 2; ks++) {
        WAIT_VM4();  // step ks's 4 loads retired (ks+1's stay in flight)
        BAR();       // all threads: ks data ready; ks-1 reads done
        stage((ks + 2) % 3, ks + 2);  // overwrite ks-1's buffer
        compute(ks % 3);
    }
    WAIT_VM4();
    BAR();
    compute((KSTEPS - 2) % 3);
    WAIT_VM0();
    BAR();
    compute((KSTEPS - 1) % 3);

    // epilogue: C/D layout col=lane&15, row=(lane>>4)*4+reg (m89/m91-verified)
#pragma unroll
    for (int mt = 0; mt < 4; mt++) {
        const int mbase = wm * 64 + mt * 16 + lq * 4;
#pragma unroll
        for (int r = 0; r < 4; r++) {
            const int orow = om_s[mbase + r];
            if (orow >= 0) {
                float* dst = Out + (size_t)orow * 256 + n0 + wn * 64 + lm;
#pragma unroll
                for (int nt = 0; nt < 4; nt++)
                    unsafeAtomicAdd(dst + nt * 16, acc[mt][nt][r]);
            }
        }
    }
}

// --------------------------- elementwise helpers ---------------------------
struct __align__(8) bf4 { __hip_bfloat16 h[4]; };

__global__ void cast_bf16_kernel(const float* __restrict__ in,
                                 __hip_bfloat16* __restrict__ out, int n4) {
    int stride = gridDim.x * blockDim.x;
    for (int i = blockIdx.x * blockDim.x + threadIdx.x; i < n4; i += stride) {
        float4 v = ((const float4*)in)[i];
        bf4 o;
        o.h[0] = __float2bfloat16(v.x);
        o.h[1] = __float2bfloat16(v.y);
        o.h[2] = __float2bfloat16(v.z);
        o.h[3] = __float2bfloat16(v.w);
        ((bf4*)out)[i] = o;
    }
}

// WT[k][n][kk] = W[k][kk][n]  (cast to bf16)
__global__ void transpose_cast_w(const float* __restrict__ W,
                                 __hip_bfloat16* __restrict__ WT, int Koff,
                                 int Cin, int Cout) {
    int total = Koff * Cin * Cout;
    int stride = gridDim.x * blockDim.x;
    for (int i = blockIdx.x * blockDim.x + threadIdx.x; i < total; i += stride) {
        int k = i / (Cin * Cout);
        int r = i - k * (Cin * Cout);
        int n = r / Cin;
        int kk = r - n * Cin;
        WT[i] = __float2bfloat16(W[((size_t)k * Cin + kk) * Cout + n]);
    }
}

// X[row][0:256) = relu(bn(xa[row])), X[row][256:384) = feats_b[row]; X bf16
__global__ void bn_concat_kernel(const float* __restrict__ xa,
                                 const float* __restrict__ fb,
                                 const float* __restrict__ g,
                                 const float* __restrict__ b,
                                 const float* __restrict__ mu,
                                 const float* __restrict__ var,
                                 __hip_bfloat16* __restrict__ X) {
    const int total = 200000 * 96;  // groups of 4 channels
    int stride = gridDim.x * blockDim.x;
    for (int i = blockIdx.x * blockDim.x + threadIdx.x; i < total; i += stride) {
        int row = i / 96;
        int c4 = (i - row * 96) * 4;
        float v[4];
        if (c4 < 256) {
            float4 t = *(const float4*)(xa + (size_t)row * 256 + c4);
            v[0] = t.x; v[1] = t.y; v[2] = t.z; v[3] = t.w;
#pragma unroll
            for (int j = 0; j < 4; j++) {
                int c = c4 + j;
                float s = g[c] * rsqrtf(var[c] + 1e-5f);
                v[j] = fmaxf((v[j] - mu[c]) * s + b[c], 0.0f);
            }
        } else {
            float4 t = *(const float4*)(fb + (size_t)row * 128 + (c4 - 256));
            v[0] = t.x; v[1] = t.y; v[2] = t.z; v[3] = t.w;
        }
        bf4 o;
#pragma unroll
        for (int j = 0; j < 4; j++) o.h[j] = __float2bfloat16(v[j]);
        *(bf4*)(X + (size_t)row * 384 + c4) = o;
    }
}

__global__ void bn_out_kernel(float* __restrict__ out, const float* __restrict__ g,
                              const float* __restrict__ b,
                              const float* __restrict__ mu,
                              const float* __restrict__ var) {
    const int total = 200000 * 64;  // float4 groups, 256 ch per row
    int stride = gridDim.x * blockDim.x;
    for (int i = blockIdx.x * blockDim.x + threadIdx.x; i < total; i += stride) {
        int c4 = (i & 63) * 4;
        float4 t = ((const float4*)out)[i];
        float v[4] = {t.x, t.y, t.z, t.w};
#pragma unroll
        for (int j = 0; j < 4; j++) {
            int c = c4 + j;
            float s = g[c] * rsqrtf(var[c] + 1e-5f);
            v[j] = fmaxf((v[j] - mu[c]) * s + b[c], 0.0f);
        }
        ((float4*)out)[i] = make_float4(v[0], v[1], v[2], v[3]);
    }
}

// ---------------------------------------------------------------------------
extern "C" void kernel_launch(void* const* d_in, const int* in_sizes, int n_in,
                              void* d_out, int out_size, void* d_ws,
                              size_t ws_size, hipStream_t stream) {
    const float* feats_a = (const float*)d_in[0];
    const float* feats_b = (const float*)d_in[1];
    const float* W_t = (const float*)d_in[2];
    const float* bn_t_gamma = (const float*)d_in[3];
    const float* bn_t_beta = (const float*)d_in[4];
    const float* bn_t_mean = (const float*)d_in[5];
    const float* bn_t_var = (const float*)d_in[6];
    const float* W_c = (const float*)d_in[7];
    const float* bn_c_gamma = (const float*)d_in[8];
    const float* bn_c_beta = (const float*)d_in[9];
    const float* bn_c_mean = (const float*)d_in[10];
    const float* bn_c_var = (const float*)d_in[11];
    const int* in_map_t = (const int*)d_in[12];
    const int* out_map_t = (const int*)d_in[13];
    const int* in_map_c = (const int*)d_in[14];
    const int* out_map_c = (const int*)d_in[15];
    float* out = (float*)d_out;

    // workspace layout (all 16B aligned)
    char* ws = (char*)d_ws;
    __hip_bfloat16* a_bf = (__hip_bfloat16*)ws;                    // 50000*256*2   = 25,600,000
    __hip_bfloat16* wtT = (__hip_bfloat16*)(ws + 25600000);        // 8*256*256*2   =  1,048,576
    __hip_bfloat16* wcT = (__hip_bfloat16*)(ws + 26648576);        // 27*256*384*2  =  5,308,416
    __hip_bfloat16* x_bf = (__hip_bfloat16*)(ws + 31956992);       // 200000*384*2  = 153,600,000

    cast_bf16_kernel<<<512, 256, 0, stream>>>(feats_a, a_bf, 50000 * 256 / 4);
    transpose_cast_w<<<512, 256, 0, stream>>>(W_t, wtT, 8, 256, 256);
    transpose_cast_w<<<512, 256, 0, stream>>>(W_c, wcT, 27, 384, 256);

    hipMemsetAsync(d_out, 0, (size_t)out_size * sizeof(float), stream);
    dim3 g1(782, 2, 8);  // ceil(100000/128) m-tiles, 2 n-blocks, 8 offsets
    spconv_kernel<8><<<g1, 256, 0, stream>>>(a_bf, wtT, in_map_t, out_map_t, out, 100000);

    bn_concat_kernel<<<2048, 256, 0, stream>>>(out, feats_b, bn_t_gamma, bn_t_beta,
                                               bn_t_mean, bn_t_var, x_bf);

    hipMemsetAsync(d_out, 0, (size_t)out_size * sizeof(float), stream);
    dim3 g2(938, 2, 27);  // ceil(120000/128) m-tiles, 2 n-blocks, 27 offsets
    spconv_kernel<12><<<g2, 256, 0, stream>>>(x_bf, wcT, in_map_c, out_map_c, out, 120000);

    bn_out_kernel<<<2048, 256, 0, stream>>>(out, bn_c_gamma, bn_c_beta, bn_c_mean,
                                            bn_c_var);
}